// Round 1
// baseline (270.369 us; speedup 1.0000x reference)
//
#include <hip/hip_runtime.h>
#include <stdint.h>

#define BS 8
#define V 4096
#define C 64
#define A 12
#define KNB 4
#define POOL 1024
#define CC 512            // candidates per chunk
#define NCC (V / CC)      // 8
#define QPB 256           // queries per block
#define NQC (POOL / QPB)  // 4

// ---------------------------------------------------------------------------
// Kernel 1: per-(batch, query-chunk, candidate-chunk) partial top-5.
// Candidates staged in LDS as (x,y,z,quad); all lanes iterate candidates in
// lockstep -> uniform-address LDS broadcast (conflict-free, 1 read/wave).
// Key = orderable-float-bits(dist)<<32 | idx  => u64 min == (dist asc, idx asc)
// which reproduces jax.lax.top_k(-dist) ordering incl. tie-break.
// ---------------------------------------------------------------------------
__global__ __launch_bounds__(256) void knn_chunk_kernel(
    const float* __restrict__ vtx,                 // [BS][V][3]
    const int* __restrict__ sidx,                  // [POOL]
    unsigned long long* __restrict__ partial)      // [BS*POOL][NCC*5]
{
    __shared__ float4 cand[CC];

    const int bid = blockIdx.x;
    const int cc = bid % NCC;
    const int qc = (bid / NCC) % NQC;
    const int b  = bid / (NCC * NQC);
    const int tid = threadIdx.x;

    const float* vb = vtx + (size_t)b * V * 3;

    // stage candidate chunk into LDS with precomputed quad
    for (int t = tid; t < CC; t += 256) {
        const int j = cc * CC + t;
        const float x = vb[j * 3 + 0];
        const float y = vb[j * 3 + 1];
        const float z = vb[j * 3 + 2];
        float q;
        {
#pragma clang fp contract(off)
            q = (x * x + y * y) + z * z;   // match XLA: separate mul, then sum
        }
        cand[t] = make_float4(x, y, z, q);
    }
    __syncthreads();

    const int s = qc * QPB + tid;          // pooled query index 0..1023
    const int gq = sidx[s];                // global vertex id of query
    const float qx = vb[gq * 3 + 0];
    const float qy = vb[gq * 3 + 1];
    const float qz = vb[gq * 3 + 2];
    float qq;
    {
#pragma clang fp contract(off)
        qq = (qx * qx + qy * qy) + qz * qz;
    }

    unsigned long long k0 = ~0ull, k1 = ~0ull, k2 = ~0ull, k3 = ~0ull, k4 = ~0ull;

#pragma unroll 8
    for (int jj = 0; jj < CC; ++jj) {
        const float4 cd = cand[jj];
        // inner = fma chain over c=0,1,2 (XLA dot with K=3)
        const float inner = fmaf(cd.z, qz, fmaf(cd.y, qy, cd.x * qx));
        // dist = ((-2*inner) + quad_j) + quad_i ; -2*inner exact => fma legal
        const float d = fmaf(-2.0f, inner, cd.w) + qq;
        const unsigned int bits = __float_as_uint(d);
        const unsigned int msk = (unsigned int)(((int)bits) >> 31) | 0x80000000u;
        const unsigned int u = bits ^ msk;   // orderable uint
        const unsigned long long key =
            ((unsigned long long)u << 32) | (unsigned int)(cc * CC + jj);
        if (key < k4) {
            k4 = key;
            if (k4 < k3) { unsigned long long t = k3; k3 = k4; k4 = t; }
            if (k3 < k2) { unsigned long long t = k2; k2 = k3; k3 = t; }
            if (k2 < k1) { unsigned long long t = k1; k1 = k2; k2 = t; }
            if (k1 < k0) { unsigned long long t = k0; k0 = k1; k1 = t; }
        }
    }

    const size_t off = ((size_t)(b * POOL + s) * NCC + cc) * 5;
    partial[off + 0] = k0;
    partial[off + 1] = k1;
    partial[off + 2] = k2;
    partial[off + 3] = k3;
    partial[off + 4] = k4;
}

// ---------------------------------------------------------------------------
// Kernel 2: merge 8 partial top-5 lists -> global top-5; drop rank 0 (self),
// emit 4 neighbor indices. Also writes vertices_pool output.
// ---------------------------------------------------------------------------
__global__ __launch_bounds__(256) void knn_merge_kernel(
    const unsigned long long* __restrict__ partial,  // [BS*POOL][NCC*5]
    const float* __restrict__ vtx,                   // [BS][V][3]
    const int* __restrict__ sidx,                    // [POOL]
    int* __restrict__ nbr,                           // [BS*POOL][4]
    float* __restrict__ outv)                        // [BS][POOL][3]
{
    const int t = blockIdx.x * 256 + threadIdx.x;    // 0..BS*POOL-1
    if (t >= BS * POOL) return;
    const int b = t / POOL;
    const int s = t % POOL;

    const unsigned long long* p = partial + (size_t)t * (NCC * 5);
    unsigned long long k0 = ~0ull, k1 = ~0ull, k2 = ~0ull, k3 = ~0ull, k4 = ~0ull;
#pragma unroll
    for (int i = 0; i < NCC * 5; ++i) {
        const unsigned long long key = p[i];
        if (key < k4) {
            k4 = key;
            if (k4 < k3) { unsigned long long tt = k3; k3 = k4; k4 = tt; }
            if (k3 < k2) { unsigned long long tt = k2; k2 = k3; k3 = tt; }
            if (k2 < k1) { unsigned long long tt = k1; k1 = k2; k2 = tt; }
            if (k1 < k0) { unsigned long long tt = k0; k0 = k1; k1 = tt; }
        }
    }
    // ranks 1..4 = neighbors (rank 0 is self, dist == 0 exactly)
    int4 nb;
    nb.x = (int)(unsigned int)k1;
    nb.y = (int)(unsigned int)k2;
    nb.z = (int)(unsigned int)k3;
    nb.w = (int)(unsigned int)k4;
    ((int4*)nbr)[t] = nb;

    // vertices_pool
    const int gq = sidx[s];
    const float* vv = vtx + ((size_t)b * V + gq) * 3;
    outv[(size_t)t * 3 + 0] = vv[0];
    outv[(size_t)t * 3 + 1] = vv[1];
    outv[(size_t)t * 3 + 2] = vv[2];
}

// ---------------------------------------------------------------------------
// Kernel 3: gather 4 neighbor feature rows (12 floats each) per (b,c,s),
// max-pool over k, write [BS][C][POOL][A]. Rows are 48B = 3 x float4, aligned.
// ---------------------------------------------------------------------------
__device__ inline float4 f4max(float4 a, float4 b) {
    return make_float4(fmaxf(a.x, b.x), fmaxf(a.y, b.y),
                       fmaxf(a.z, b.z), fmaxf(a.w, b.w));
}

__global__ __launch_bounds__(256) void gather_pool_kernel(
    const float* __restrict__ fm,     // [BS][C][V][A]
    const int* __restrict__ nbr,      // [BS*POOL][4]
    float* __restrict__ outf)         // [BS][C][POOL][A]
{
    const int t = blockIdx.x * 256 + threadIdx.x;  // 0..BS*C*POOL-1
    const int s = t % POOL;
    const int c = (t / POOL) % C;
    const int b = t / (POOL * C);

    const int4 nb = ((const int4*)nbr)[b * POOL + s];

    const float4* base = (const float4*)fm + (size_t)(b * C + c) * V * 3;

    float4 r0 = base[(size_t)nb.x * 3 + 0];
    float4 r1 = base[(size_t)nb.x * 3 + 1];
    float4 r2 = base[(size_t)nb.x * 3 + 2];

    float4 s0 = base[(size_t)nb.y * 3 + 0];
    float4 s1 = base[(size_t)nb.y * 3 + 1];
    float4 s2 = base[(size_t)nb.y * 3 + 2];
    r0 = f4max(r0, s0); r1 = f4max(r1, s1); r2 = f4max(r2, s2);

    s0 = base[(size_t)nb.z * 3 + 0];
    s1 = base[(size_t)nb.z * 3 + 1];
    s2 = base[(size_t)nb.z * 3 + 2];
    r0 = f4max(r0, s0); r1 = f4max(r1, s1); r2 = f4max(r2, s2);

    s0 = base[(size_t)nb.w * 3 + 0];
    s1 = base[(size_t)nb.w * 3 + 1];
    s2 = base[(size_t)nb.w * 3 + 2];
    r0 = f4max(r0, s0); r1 = f4max(r1, s1); r2 = f4max(r2, s2);

    float4* dst = (float4*)outf + (size_t)t * 3;
    dst[0] = r0;
    dst[1] = r1;
    dst[2] = r2;
}

// ---------------------------------------------------------------------------
extern "C" void kernel_launch(void* const* d_in, const int* in_sizes, int n_in,
                              void* d_out, int out_size, void* d_ws, size_t ws_size,
                              hipStream_t stream) {
    const float* vtx = (const float*)d_in[0];   // vertices  [BS][V][3]
    const float* fm  = (const float*)d_in[1];   // feature_map [BS][C][V][A]
    const int* sidx  = (const int*)d_in[2];     // sample_idx [POOL]
    float* out = (float*)d_out;

    // workspace layout
    unsigned long long* partial = (unsigned long long*)d_ws;            // 8192*40*8 B
    const size_t partial_bytes = (size_t)BS * POOL * NCC * 5 * sizeof(unsigned long long);
    int* nbr = (int*)((char*)d_ws + partial_bytes);                     // 8192*4*4 B

    float* outv = out;                       // [BS][POOL][3]
    float* outf = out + (size_t)BS * POOL * 3;  // [BS][C][POOL][A]

    knn_chunk_kernel<<<BS * NQC * NCC, 256, 0, stream>>>(vtx, sidx, partial);
    knn_merge_kernel<<<(BS * POOL) / 256, 256, 0, stream>>>(partial, vtx, sidx, nbr, outv);
    gather_pool_kernel<<<(BS * C * POOL) / 256, 256, 0, stream>>>(fm, nbr, outf);
}

// Round 2
// 225.748 us; speedup vs baseline: 1.1977x; 1.1977x over previous
//
#include <hip/hip_runtime.h>
#include <stdint.h>

#define BS 8
#define V 4096
#define C 64
#define A 12
#define POOL 1024

// ---------------------------------------------------------------------------
// Kernel 1: per-(batch, query-chunk, candidate-chunk) partial top-5.
// Candidates staged in LDS as (x,y,z,quad); lanes iterate in lockstep ->
// uniform-address broadcast (conflict-free).
// Top-5 kept as separate hi (orderable dist bits) / lo (index) registers.
// Monotone-index trick: scan order => new idx > all stored idx, so the u64
// key compare (dist,idx) reduces to a STRICT 32-bit compare on hi.
// ---------------------------------------------------------------------------
template<int NCC>
__global__ __launch_bounds__(256) void knn_chunk_kernel(
    const float* __restrict__ vtx,                 // [BS][V][3]
    const int* __restrict__ sidx,                  // [POOL]
    unsigned long long* __restrict__ partial)      // [BS*POOL][NCC*5]
{
    constexpr int CC = V / NCC;
    __shared__ float4 cand[CC];

    const int bid = blockIdx.x;
    const int cc = bid % NCC;
    const int qc = (bid / NCC) & 3;        // NQC = 4
    const int b  = bid / (NCC * 4);
    const int tid = threadIdx.x;

    const float* vb = vtx + (size_t)b * V * 3;

    for (int t = tid; t < CC; t += 256) {
        const int j = cc * CC + t;
        const float x = vb[j * 3 + 0];
        const float y = vb[j * 3 + 1];
        const float z = vb[j * 3 + 2];
        float q;
        {
#pragma clang fp contract(off)
            q = (x * x + y * y) + z * z;   // match XLA: elementwise mul, then sum
        }
        cand[t] = make_float4(x, y, z, q);
    }
    __syncthreads();

    const int s = qc * 256 + tid;          // pooled query index 0..1023
    const int gq = sidx[s];
    const float qx = vb[gq * 3 + 0];
    const float qy = vb[gq * 3 + 1];
    const float qz = vb[gq * 3 + 2];
    float qq;
    {
#pragma clang fp contract(off)
        qq = (qx * qx + qy * qy) + qz * qz;
    }

    unsigned int h0 = ~0u, h1 = ~0u, h2 = ~0u, h3 = ~0u, h4 = ~0u;
    unsigned int l0 = 0, l1 = 0, l2 = 0, l3 = 0, l4 = 0;

#pragma unroll 8
    for (int jj = 0; jj < CC; ++jj) {
        const float4 cd = cand[jj];
        const float inner = fmaf(cd.z, qz, fmaf(cd.y, qy, cd.x * qx));
        const float d = fmaf(-2.0f, inner, cd.w) + qq;   // -2*inner exact
        const unsigned int bits = __float_as_uint(d);
        const unsigned int u = bits ^ ((unsigned int)(((int)bits) >> 31) | 0x80000000u);
        const unsigned int idx = (unsigned int)(cc * CC + jj);
        if (u < h4) {   // strict: ties lose to smaller stored idx
            const bool c0 = u < h0, c1 = u < h1, c2 = u < h2, c3 = u < h3;
            h4 = c3 ? h3 : u;              l4 = c3 ? l3 : idx;
            h3 = c3 ? (c2 ? h2 : u) : h3;  l3 = c3 ? (c2 ? l2 : idx) : l3;
            h2 = c2 ? (c1 ? h1 : u) : h2;  l2 = c2 ? (c1 ? l1 : idx) : l2;
            h1 = c1 ? (c0 ? h0 : u) : h1;  l1 = c1 ? (c0 ? l0 : idx) : l1;
            h0 = c0 ? u : h0;              l0 = c0 ? idx : l0;
        }
    }

    unsigned long long* p = partial + ((size_t)(b * POOL + s) * NCC + cc) * 5;
    p[0] = ((unsigned long long)h0 << 32) | l0;
    p[1] = ((unsigned long long)h1 << 32) | l1;
    p[2] = ((unsigned long long)h2 << 32) | l2;
    p[3] = ((unsigned long long)h3 << 32) | l3;
    p[4] = ((unsigned long long)h4 << 32) | l4;
}

// ---------------------------------------------------------------------------
// Kernel 2: merge NCC sorted 5-lists -> global top-5; drop rank 0 (self).
// Chunks visited in ascending-index order, each chunk internally sorted by
// (dist,idx) => monotone-index trick again: strict 32-bit hi compares only.
// Exact chunk skip: if chunk's best hi >= h4, nothing in it can enter.
// ---------------------------------------------------------------------------
template<int NCC>
__global__ __launch_bounds__(256) void knn_merge_kernel(
    const unsigned long long* __restrict__ partial,  // [BS*POOL][NCC*5]
    const float* __restrict__ vtx,                   // [BS][V][3]
    const int* __restrict__ sidx,                    // [POOL]
    int* __restrict__ nbr,                           // [BS*POOL][4]
    float* __restrict__ outv)                        // [BS][POOL][3]
{
    const int t = blockIdx.x * 256 + threadIdx.x;    // 0..BS*POOL-1
    const int b = t / POOL;
    const int s = t % POOL;

    const unsigned long long* p = partial + (size_t)t * (NCC * 5);

    unsigned int h0 = ~0u, h1 = ~0u, h2 = ~0u, h3 = ~0u, h4 = ~0u;
    unsigned int l0 = 0, l1 = 0, l2 = 0, l3 = 0, l4 = 0;

#pragma unroll 4
    for (int ccc = 0; ccc < NCC; ++ccc) {
        const unsigned long long a0 = p[ccc * 5 + 0];
        const unsigned long long a1 = p[ccc * 5 + 1];
        const unsigned long long a2 = p[ccc * 5 + 2];
        const unsigned long long a3 = p[ccc * 5 + 3];
        const unsigned long long a4 = p[ccc * 5 + 4];
        if ((unsigned int)(a0 >> 32) < h4) {
#define INS(K)                                                               \
            {                                                                \
                const unsigned int u = (unsigned int)((K) >> 32);            \
                const unsigned int idx = (unsigned int)(K);                  \
                const bool c0 = u < h0, c1 = u < h1, c2 = u < h2,            \
                           c3 = u < h3, c4 = u < h4;                         \
                h4 = c4 ? (c3 ? h3 : u) : h4;                                \
                l4 = c4 ? (c3 ? l3 : idx) : l4;                              \
                h3 = c3 ? (c2 ? h2 : u) : h3;                                \
                l3 = c3 ? (c2 ? l2 : idx) : l3;                              \
                h2 = c2 ? (c1 ? h1 : u) : h2;                                \
                l2 = c2 ? (c1 ? l1 : idx) : l2;                              \
                h1 = c1 ? (c0 ? h0 : u) : h1;                                \
                l1 = c1 ? (c0 ? l0 : idx) : l1;                              \
                h0 = c0 ? u : h0;                                            \
                l0 = c0 ? idx : l0;                                          \
            }
            INS(a0) INS(a1) INS(a2) INS(a3) INS(a4)
#undef INS
        }
    }

    // ranks 1..4 = neighbors (rank 0 is self)
    int4 nb;
    nb.x = (int)l1;
    nb.y = (int)l2;
    nb.z = (int)l3;
    nb.w = (int)l4;
    ((int4*)nbr)[t] = nb;

    const int gq = sidx[s];
    const float* vv = vtx + ((size_t)b * V + gq) * 3;
    outv[(size_t)t * 3 + 0] = vv[0];
    outv[(size_t)t * 3 + 1] = vv[1];
    outv[(size_t)t * 3 + 2] = vv[2];
}

// ---------------------------------------------------------------------------
// Kernel 3: gather 4 neighbor feature rows (12 floats = 3 x float4, aligned)
// per (b,c,s), max-pool over k, write [BS][C][POOL][A].
// ---------------------------------------------------------------------------
__device__ inline float4 f4max(float4 a, float4 b) {
    return make_float4(fmaxf(a.x, b.x), fmaxf(a.y, b.y),
                       fmaxf(a.z, b.z), fmaxf(a.w, b.w));
}

__global__ __launch_bounds__(256) void gather_pool_kernel(
    const float* __restrict__ fm,     // [BS][C][V][A]
    const int* __restrict__ nbr,      // [BS*POOL][4]
    float* __restrict__ outf)         // [BS][C][POOL][A]
{
    const int t = blockIdx.x * 256 + threadIdx.x;  // 0..BS*C*POOL-1
    const int s = t % POOL;
    const int c = (t / POOL) % C;
    const int b = t / (POOL * C);

    const int4 nb = ((const int4*)nbr)[b * POOL + s];

    const float4* base = (const float4*)fm + (size_t)(b * C + c) * V * 3;

    float4 r0 = base[(size_t)nb.x * 3 + 0];
    float4 r1 = base[(size_t)nb.x * 3 + 1];
    float4 r2 = base[(size_t)nb.x * 3 + 2];

    float4 s0 = base[(size_t)nb.y * 3 + 0];
    float4 s1 = base[(size_t)nb.y * 3 + 1];
    float4 s2 = base[(size_t)nb.y * 3 + 2];
    r0 = f4max(r0, s0); r1 = f4max(r1, s1); r2 = f4max(r2, s2);

    s0 = base[(size_t)nb.z * 3 + 0];
    s1 = base[(size_t)nb.z * 3 + 1];
    s2 = base[(size_t)nb.z * 3 + 2];
    r0 = f4max(r0, s0); r1 = f4max(r1, s1); r2 = f4max(r2, s2);

    s0 = base[(size_t)nb.w * 3 + 0];
    s1 = base[(size_t)nb.w * 3 + 1];
    s2 = base[(size_t)nb.w * 3 + 2];
    r0 = f4max(r0, s0); r1 = f4max(r1, s1); r2 = f4max(r2, s2);

    float4* dst = (float4*)outf + (size_t)t * 3;
    dst[0] = r0;
    dst[1] = r1;
    dst[2] = r2;
}

// ---------------------------------------------------------------------------
extern "C" void kernel_launch(void* const* d_in, const int* in_sizes, int n_in,
                              void* d_out, int out_size, void* d_ws, size_t ws_size,
                              hipStream_t stream) {
    const float* vtx = (const float*)d_in[0];   // vertices  [BS][V][3]
    const float* fm  = (const float*)d_in[1];   // feature_map [BS][C][V][A]
    const int* sidx  = (const int*)d_in[2];     // sample_idx [POOL]
    float* out = (float*)d_out;

    float* outv = out;                          // [BS][POOL][3]
    float* outf = out + (size_t)BS * POOL * 3;  // [BS][C][POOL][A]

    unsigned long long* partial = (unsigned long long*)d_ws;

    const size_t need32 = (size_t)BS * POOL * 32 * 5 * 8 + (size_t)BS * POOL * 16;

    if (ws_size >= need32) {
        constexpr int NCC = 32;
        int* nbr = (int*)((char*)d_ws + (size_t)BS * POOL * NCC * 5 * 8);
        knn_chunk_kernel<NCC><<<BS * 4 * NCC, 256, 0, stream>>>(vtx, sidx, partial);
        knn_merge_kernel<NCC><<<(BS * POOL) / 256, 256, 0, stream>>>(partial, vtx, sidx, nbr, outv);
        gather_pool_kernel<<<(BS * C * POOL) / 256, 256, 0, stream>>>(fm, nbr, outf);
    } else {
        constexpr int NCC = 16;
        int* nbr = (int*)((char*)d_ws + (size_t)BS * POOL * NCC * 5 * 8);
        knn_chunk_kernel<NCC><<<BS * 4 * NCC, 256, 0, stream>>>(vtx, sidx, partial);
        knn_merge_kernel<NCC><<<(BS * POOL) / 256, 256, 0, stream>>>(partial, vtx, sidx, nbr, outv);
        gather_pool_kernel<<<(BS * C * POOL) / 256, 256, 0, stream>>>(fm, nbr, outf);
    }
}